// Round 1
// baseline (15889.688 us; speedup 1.0000x reference)
//
#include <hip/hip_runtime.h>
#include <cstddef>

// Bigram CE: logits = emb[seq] @ W^T + b  (fp32), loss = mean CE.
// Fused: GEMM + streaming store of logits + online per-row sum(exp(x)).
// N=4096 rows, V=100277 vocab, E=32.

constexpr int TM  = 16;   // rows per block
constexpr int TV  = 4;    // vocab columns per thread per sweep step
constexpr int TPB = 512;  // threads per block (8 waves)

__global__ __launch_bounds__(TPB) void bigram_logits_rowsum(
    const int*   __restrict__ seq,
    const float* __restrict__ emb,
    const float* __restrict__ W,
    const float* __restrict__ bias,
    float*       __restrict__ logits,
    float*       __restrict__ rowsum,
    int N, int V)
{
    __shared__ float4 e4s[TM][8];           // 16 rows x 32 floats of embeddings
    __shared__ float  red[TM][TPB / 64 + 1];

    const int tid  = threadIdx.x;
    const int row0 = blockIdx.x * TM;

    // Stage embeddings: 16*32 = 512 floats, one per thread.
    {
        const int m = tid >> 5;
        const int k = tid & 31;
        const int r = seq[row0 + m];
        reinterpret_cast<float*>(&e4s[m][0])[k] = emb[(size_t)r * 32 + k];
    }
    __syncthreads();

    float sums[TM];
#pragma unroll
    for (int m = 0; m < TM; ++m) sums[m] = 0.f;

    const int VSTEP = TPB * TV;  // 2048 columns per sweep step

    for (int vb = 0; vb < V; vb += VSTEP) {
        int v[TV], cv[TV];
#pragma unroll
        for (int vv = 0; vv < TV; ++vv) {
            v[vv]  = vb + tid + vv * TPB;          // column strided by TPB -> coalesced stores
            cv[vv] = v[vv] < V ? v[vv] : V - 1;     // clamped index for safe loads in tail
        }

        float4 acc[TM];
        {
            const float b0 = bias[cv[0]], b1 = bias[cv[1]], b2 = bias[cv[2]], b3 = bias[cv[3]];
#pragma unroll
            for (int m = 0; m < TM; ++m) acc[m] = make_float4(b0, b1, b2, b3);
        }

        const float* __restrict__ wp0 = W + (size_t)cv[0] * 32;
        const float* __restrict__ wp1 = W + (size_t)cv[1] * 32;
        const float* __restrict__ wp2 = W + (size_t)cv[2] * 32;
        const float* __restrict__ wp3 = W + (size_t)cv[3] * 32;

#pragma unroll
        for (int k4 = 0; k4 < 8; ++k4) {
            const float4 w0 = *reinterpret_cast<const float4*>(wp0 + 4 * k4);
            const float4 w1 = *reinterpret_cast<const float4*>(wp1 + 4 * k4);
            const float4 w2 = *reinterpret_cast<const float4*>(wp2 + 4 * k4);
            const float4 w3 = *reinterpret_cast<const float4*>(wp3 + 4 * k4);
#pragma unroll
            for (int m = 0; m < TM; ++m) {
                const float4 e = e4s[m][k4];   // uniform address -> LDS broadcast
                acc[m].x += e.x * w0.x + e.y * w0.y + e.z * w0.z + e.w * w0.w;
                acc[m].y += e.x * w1.x + e.y * w1.y + e.z * w1.z + e.w * w1.w;
                acc[m].z += e.x * w2.x + e.y * w2.y + e.z * w2.z + e.w * w2.w;
                acc[m].w += e.x * w3.x + e.y * w3.y + e.z * w3.z + e.w * w3.w;
            }
        }

        // Epilogue: streaming store + online sum(exp(x)).
#pragma unroll
        for (int m = 0; m < TM; ++m) {
            float* lrow = logits + (size_t)(row0 + m) * V;
            const float xs[TV] = {acc[m].x, acc[m].y, acc[m].z, acc[m].w};
#pragma unroll
            for (int vv = 0; vv < TV; ++vv) {
                if (v[vv] < V) {
                    __builtin_nontemporal_store(xs[vv], &lrow[v[vv]]);
                    sums[m] += __expf(xs[vv]);
                }
            }
        }
    }

    // Block-level reduction of per-thread partial sums, per row.
#pragma unroll
    for (int m = 0; m < TM; ++m) {
        float s = sums[m];
#pragma unroll
        for (int off = 32; off >= 1; off >>= 1) s += __shfl_xor(s, off, 64);
        if ((tid & 63) == 0) red[m][tid >> 6] = s;
    }
    __syncthreads();
    if (tid < TM) {
        float s = 0.f;
#pragma unroll
        for (int w = 0; w < TPB / 64; ++w) s += red[tid][w];
        rowsum[row0 + tid] = s;
    }
}

// Finalize: nll_n = log(sum_exp_n) - (dot(emb[seq[n]], W[pred[n]]) + b[pred[n]]);
// loss = mean(nll). Tiny: 4096 rows x 32 FMA.
__global__ void bigram_loss(
    const int*   __restrict__ seq,
    const int*   __restrict__ pred,
    const float* __restrict__ emb,
    const float* __restrict__ W,
    const float* __restrict__ bias,
    const float* __restrict__ rowsum,
    float*       __restrict__ loss,
    int N)
{
    const int tid = threadIdx.x;
    float local = 0.f;
    for (int n = blockIdx.x * blockDim.x + tid; n < N; n += gridDim.x * blockDim.x) {
        const int r = seq[n], t = pred[n];
        const float4* e4 = reinterpret_cast<const float4*>(emb + (size_t)r * 32);
        const float4* w4 = reinterpret_cast<const float4*>(W + (size_t)t * 32);
        float d = bias[t];
#pragma unroll
        for (int i = 0; i < 8; ++i) {
            const float4 e = e4[i], w = w4[i];
            d += e.x * w.x + e.y * w.y + e.z * w.z + e.w * w.w;
        }
        local += __logf(rowsum[n]) - d;
    }
#pragma unroll
    for (int off = 32; off >= 1; off >>= 1) local += __shfl_xor(local, off, 64);
    __shared__ float r4[4];
    if ((tid & 63) == 0) r4[tid >> 6] = local;
    __syncthreads();
    if (tid == 0) {
        const float s = r4[0] + r4[1] + r4[2] + r4[3];
        atomicAdd(loss, s / (float)N);
    }
}

extern "C" void kernel_launch(void* const* d_in, const int* in_sizes, int n_in,
                              void* d_out, int out_size, void* d_ws, size_t ws_size,
                              hipStream_t stream)
{
    const int*   seq  = (const int*)d_in[0];
    const int*   pred = (const int*)d_in[1];
    const float* emb  = (const float*)d_in[2];
    const float* W    = (const float*)d_in[3];
    const float* bias = (const float*)d_in[4];

    const int N = in_sizes[0];      // 4096
    const int V = in_sizes[4];      // 100277

    float* logits = (float*)d_out;
    float* loss   = logits + (size_t)N * V;   // second output, concatenated flat
    float* rowsum = (float*)d_ws;             // N floats of scratch

    // loss is accumulated via atomicAdd from 16 blocks -> zero it first.
    hipMemsetAsync((void*)loss, 0, sizeof(float), stream);

    const int grid = N / TM;  // 256 blocks, one per CU
    hipLaunchKernelGGL(bigram_logits_rowsum, dim3(grid), dim3(TPB), 0, stream,
                       seq, emb, W, bias, logits, rowsum, N, V);
    hipLaunchKernelGGL(bigram_loss, dim3(16), dim3(256), 0, stream,
                       seq, pred, emb, W, bias, rowsum, loss, N);
}

// Round 2
// 1028.035 us; speedup vs baseline: 15.4564x; 15.4564x over previous
//
#include <hip/hip_runtime.h>
#include <cstddef>

// Bigram CE: logits = emb[seq] @ W^T + b (fp32), loss = mean CE.
// V-tiled: each wave owns 128 vocab columns (W held in 64 VGPRs) and sweeps
// 512 rows. Plain write-back stores (NO nontemporal). Row-sum of exp via one
// HW fp-atomic per (wave,row), rotated to avoid synchronized bursts.

constexpr int COLS_PER_WAVE  = 128;  // 2 per lane
constexpr int WAVES_PER_BLOCK = 4;
constexpr int ROW_SPLITS      = 8;   // 4096 rows -> 8 chunks of 512

__global__ __launch_bounds__(256, 4) void bigram_fused(
    const int*   __restrict__ seq,
    const float* __restrict__ emb,
    const float* __restrict__ W,
    const float* __restrict__ bias,
    float*       __restrict__ logits,
    float*       __restrict__ rowsum,
    int N, int V, int nslices)
{
    const int tid    = threadIdx.x;
    const int lane   = tid & 63;
    const int wid    = tid >> 6;
    const int vslice = blockIdx.x % nslices;
    const int rhalf  = blockIdx.x / nslices;                 // 0 or 1
    const int rsplit = rhalf * WAVES_PER_BLOCK + wid;        // 0..7
    const int rowsPer = N / ROW_SPLITS;                      // 512 (pow2)
    const int n0 = rsplit * rowsPer;

    const int c0 = vslice * COLS_PER_WAVE + lane;
    const int c1 = c0 + 64;
    const bool ok0 = c0 < V, ok1 = c1 < V;
    const int cc0 = ok0 ? c0 : V - 1;
    const int cc1 = ok1 ? c1 : V - 1;

    // W rows for this lane's two columns -> registers (loaded once).
    float w0[32], w1[32];
    {
        const float4* p0 = reinterpret_cast<const float4*>(W + (size_t)cc0 * 32);
        const float4* p1 = reinterpret_cast<const float4*>(W + (size_t)cc1 * 32);
#pragma unroll
        for (int i = 0; i < 8; ++i) {
            const float4 a = p0[i], b = p1[i];
            w0[4*i+0]=a.x; w0[4*i+1]=a.y; w0[4*i+2]=a.z; w0[4*i+3]=a.w;
            w1[4*i+0]=b.x; w1[4*i+1]=b.y; w1[4*i+2]=b.z; w1[4*i+3]=b.w;
        }
    }
    const float b0 = bias[cc0];
    const float b1 = bias[cc1];

    // Rotate row order per slice so same-row atomics from different slices
    // don't arrive as a synchronized burst.
    const int rot = vslice & (rowsPer - 1);

    for (int ii = 0; ii < rowsPer; ++ii) {
        const int n = n0 + ((ii + rot) & (rowsPer - 1));
        const int idx = __builtin_amdgcn_readfirstlane(seq[n]);
        const float4* e4 = reinterpret_cast<const float4*>(emb + (size_t)idx * 32);

        float x0 = b0, x1 = b1;
#pragma unroll
        for (int i = 0; i < 8; ++i) {
            const float4 e = e4[i];   // uniform address -> scalar/broadcast load
            x0 = fmaf(e.x, w0[4*i+0], x0); x1 = fmaf(e.x, w1[4*i+0], x1);
            x0 = fmaf(e.y, w0[4*i+1], x0); x1 = fmaf(e.y, w1[4*i+1], x1);
            x0 = fmaf(e.z, w0[4*i+2], x0); x1 = fmaf(e.z, w1[4*i+2], x1);
            x0 = fmaf(e.w, w0[4*i+3], x0); x1 = fmaf(e.w, w1[4*i+3], x1);
        }

        float* lrow = logits + (size_t)n * V;
        float s = 0.f;
        if (ok0) { lrow[c0] = x0; s += __expf(x0); }   // coalesced 256B/wave
        if (ok1) { lrow[c1] = x1; s += __expf(x1); }

#pragma unroll
        for (int off = 32; off >= 1; off >>= 1) s += __shfl_xor(s, off, 64);
        if (lane == 0)
            __hip_atomic_fetch_add(&rowsum[n], s, __ATOMIC_RELAXED,
                                   __HIP_MEMORY_SCOPE_AGENT);
    }
}

// Finalize: nll_n = log(sum_exp_n) - (dot(emb[seq[n]], W[pred[n]]) + b[pred[n]]);
// loss = mean(nll).
__global__ void bigram_loss(
    const int*   __restrict__ seq,
    const int*   __restrict__ pred,
    const float* __restrict__ emb,
    const float* __restrict__ W,
    const float* __restrict__ bias,
    const float* __restrict__ rowsum,
    float*       __restrict__ loss,
    int N)
{
    const int tid = threadIdx.x;
    float local = 0.f;
    for (int n = blockIdx.x * blockDim.x + tid; n < N; n += gridDim.x * blockDim.x) {
        const int r = seq[n], t = pred[n];
        const float4* e4 = reinterpret_cast<const float4*>(emb + (size_t)r * 32);
        const float4* w4 = reinterpret_cast<const float4*>(W + (size_t)t * 32);
        float d = bias[t];
#pragma unroll
        for (int i = 0; i < 8; ++i) {
            const float4 e = e4[i], w = w4[i];
            d += e.x * w.x + e.y * w.y + e.z * w.z + e.w * w.w;
        }
        local += __logf(rowsum[n]) - d;
    }
#pragma unroll
    for (int off = 32; off >= 1; off >>= 1) local += __shfl_xor(local, off, 64);
    __shared__ float r4[4];
    if ((tid & 63) == 0) r4[tid >> 6] = local;
    __syncthreads();
    if (tid == 0) {
        const float s = r4[0] + r4[1] + r4[2] + r4[3];
        atomicAdd(loss, s / (float)N);
    }
}

extern "C" void kernel_launch(void* const* d_in, const int* in_sizes, int n_in,
                              void* d_out, int out_size, void* d_ws, size_t ws_size,
                              hipStream_t stream)
{
    const int*   seq  = (const int*)d_in[0];
    const int*   pred = (const int*)d_in[1];
    const float* emb  = (const float*)d_in[2];
    const float* W    = (const float*)d_in[3];
    const float* bias = (const float*)d_in[4];

    const int N = in_sizes[0];      // 4096
    const int V = in_sizes[4];      // 100277

    float* logits = (float*)d_out;
    float* loss   = logits + (size_t)N * V;   // second output, flat-concatenated
    float* rowsum = (float*)d_ws;             // N floats scratch (atomic targets)

    hipMemsetAsync((void*)rowsum, 0, (size_t)N * sizeof(float), stream);
    hipMemsetAsync((void*)loss, 0, sizeof(float), stream);

    const int nslices = (V + COLS_PER_WAVE - 1) / COLS_PER_WAVE;   // 784
    const int grid = nslices * (ROW_SPLITS / WAVES_PER_BLOCK);     // 1568

    hipLaunchKernelGGL(bigram_fused, dim3(grid), dim3(256), 0, stream,
                       seq, emb, W, bias, logits, rowsum, N, V, nslices);
    hipLaunchKernelGGL(bigram_loss, dim3(16), dim3(256), 0, stream,
                       seq, pred, emb, W, bias, rowsum, loss, N);
}

// Round 3
// 897.958 us; speedup vs baseline: 17.6954x; 1.1449x over previous
//
#include <hip/hip_runtime.h>
#include <cstddef>
#include <cstdint>

// Bigram CE via MFMA: logits = emb[seq] @ W^T + b (fp32 via bf16 hi/lo split),
// fused exp-rowsum; separate tiny loss kernel.
// N=4096 rows, V=100277, K=32 (one 16x16x32 MFMA per tile, x3 for hi/lo).

using f32x4  = __attribute__((ext_vector_type(4))) float;
using bf16x8 = __attribute__((ext_vector_type(8))) __bf16;

static __device__ __forceinline__ unsigned short f2bf_rne(float f) {
    unsigned u = __float_as_uint(f);
    unsigned r = u + 0x7FFFu + ((u >> 16) & 1u);
    return (unsigned short)(r >> 16);
}
static __device__ __forceinline__ float bf2f(unsigned short h) {
    return __uint_as_float(((unsigned)h) << 16);
}
static __device__ __forceinline__ uint4 pack8(const unsigned short* h) {
    uint4 u;
    u.x = (unsigned)h[0] | ((unsigned)h[1] << 16);
    u.y = (unsigned)h[2] | ((unsigned)h[3] << 16);
    u.z = (unsigned)h[4] | ((unsigned)h[5] << 16);
    u.w = (unsigned)h[6] | ((unsigned)h[7] << 16);
    return u;
}

constexpr int N_ROWS = 4096;
constexpr int CHUNKS = N_ROWS / 16;                    // 256 row-chunks of 16
constexpr int TILES  = 4;                              // 16-col tiles per wave
constexpr int WAVES_PB = 4;
constexpr int V_PER_BLOCK = WAVES_PB * TILES * 16;     // 256 cols per block
constexpr int ROW_SPLITS = 4;
constexpr int CHUNKS_PER_SPLIT = CHUNKS / ROW_SPLITS;  // 64

// d_ws layout (bytes)
constexpr size_t RS_OFF   = 0;                          // rowsum: 4096 f32
constexpr size_t A_HI_OFF = 16384;
constexpr size_t A_BYTES  = (size_t)CHUNKS * 64 * 16;   // 256 KB
constexpr size_t A_LO_OFF = A_HI_OFF + A_BYTES;

// Pack A = emb[seq] into MFMA fragment order, hi/lo bf16.
// Fragment (16x16x32 A): lane l -> row = l&15, k = (l>>4)*8 .. +7 (contiguous).
__global__ __launch_bounds__(256) void prep_afrag(
    const int*   __restrict__ seq,
    const float* __restrict__ emb,
    uint4*       __restrict__ a_hi,
    uint4*       __restrict__ a_lo)
{
    const int g   = blockIdx.x * 256 + threadIdx.x;    // 16384 = CHUNKS*64
    const int l   = g & 63;
    const int c   = g >> 6;
    const int row = c * 16 + (l & 15);
    const int k0  = (l >> 4) * 8;
    const int idx = seq[row];

    const float* ep = emb + (size_t)idx * 32 + k0;
    float f[8];
    *reinterpret_cast<float4*>(f)     = *reinterpret_cast<const float4*>(ep);
    *reinterpret_cast<float4*>(f + 4) = *reinterpret_cast<const float4*>(ep + 4);

    unsigned short hs[8], ls[8];
#pragma unroll
    for (int i = 0; i < 8; ++i) {
        hs[i] = f2bf_rne(f[i]);
        ls[i] = f2bf_rne(f[i] - bf2f(hs[i]));
    }
    a_hi[g] = pack8(hs);
    a_lo[g] = pack8(ls);
}

__global__ __launch_bounds__(256) void bigram_mfma(
    const float* __restrict__ W,
    const float* __restrict__ bias,
    const uint4* __restrict__ a_hi,
    const uint4* __restrict__ a_lo,
    float*       __restrict__ logits,
    float*       __restrict__ rowsum,
    int V, int nColBlocks)
{
    const int tid   = threadIdx.x;
    const int lane  = tid & 63;
    const int wid   = tid >> 6;
    const int colb  = blockIdx.x % nColBlocks;
    const int rsp   = blockIdx.x / nColBlocks;
    const int lgrp  = lane >> 4;        // 0..3
    const int lcol  = lane & 15;
    const int k0    = lgrp * 8;

    const int cbase = colb * V_PER_BLOCK + wid * (TILES * 16);

    // B fragments (W columns) -> registers, hi/lo split. Lane l: col = lane&15,
    // k = (lane>>4)*8..+7 contiguous = W[col][k0..k0+7] (W is B^T row-major).
    bf16x8 bhi[TILES], blo[TILES];
    float  bval[TILES];
    bool   ok[TILES];
#pragma unroll
    for (int t = 0; t < TILES; ++t) {
        const int col = cbase + t * 16 + lcol;
        ok[t] = (col < V);
        const int cc = ok[t] ? col : V - 1;
        const float* wp = W + (size_t)cc * 32 + k0;
        float f[8];
        *reinterpret_cast<float4*>(f)     = *reinterpret_cast<const float4*>(wp);
        *reinterpret_cast<float4*>(f + 4) = *reinterpret_cast<const float4*>(wp + 4);
        unsigned short hs[8], ls[8];
#pragma unroll
        for (int i = 0; i < 8; ++i) {
            hs[i] = f2bf_rne(f[i]);
            ls[i] = f2bf_rne(f[i] - bf2f(hs[i]));
        }
        const uint4 H = pack8(hs), L = pack8(ls);
        bhi[t]  = __builtin_bit_cast(bf16x8, H);
        blo[t]  = __builtin_bit_cast(bf16x8, L);
        bval[t] = bias[cc];
    }

    const int c_begin = rsp * CHUNKS_PER_SPLIT;
    for (int c = c_begin; c < c_begin + CHUNKS_PER_SPLIT; ++c) {
        const uint4 AH = a_hi[c * 64 + lane];
        const uint4 AL = a_lo[c * 64 + lane];
        const bf16x8 ah = __builtin_bit_cast(bf16x8, AH);
        const bf16x8 al = __builtin_bit_cast(bf16x8, AL);

        f32x4 acc[TILES];
#pragma unroll
        for (int t = 0; t < TILES; ++t) {
            f32x4 a0 = {bval[t], bval[t], bval[t], bval[t]};  // bias as C-init
            a0 = __builtin_amdgcn_mfma_f32_16x16x32_bf16(ah, bhi[t], a0, 0, 0, 0);
            a0 = __builtin_amdgcn_mfma_f32_16x16x32_bf16(al, bhi[t], a0, 0, 0, 0);
            a0 = __builtin_amdgcn_mfma_f32_16x16x32_bf16(ah, blo[t], a0, 0, 0, 0);
            acc[t] = a0;
        }

        // C/D layout (m89-verified): col = lane&15, row = (lane>>4)*4 + j.
        float sj[4] = {0.f, 0.f, 0.f, 0.f};
        const int rowb = c * 16 + lgrp * 4;
#pragma unroll
        for (int j = 0; j < 4; ++j) {
            const size_t rbase = (size_t)(rowb + j) * V + cbase + lcol;
#pragma unroll
            for (int t = 0; t < TILES; ++t) {
                if (ok[t]) {
                    const float x = acc[t][j];
                    logits[rbase + t * 16] = x;     // 4x64B segments per store
                    sj[j] += __expf(x);
                }
            }
        }
        // Reduce across the 16 lanes of each row group, then one atomic per row.
#pragma unroll
        for (int j = 0; j < 4; ++j) {
            float s = sj[j];
            s += __shfl_xor(s, 1, 64);
            s += __shfl_xor(s, 2, 64);
            s += __shfl_xor(s, 4, 64);
            s += __shfl_xor(s, 8, 64);
            if (lcol == 0)
                __hip_atomic_fetch_add(&rowsum[rowb + j], s, __ATOMIC_RELAXED,
                                       __HIP_MEMORY_SCOPE_AGENT);
        }
    }
}

// loss = mean( log(rowsum[n]) - (dot(emb[seq[n]], W[pred[n]]) + b[pred[n]]) )
__global__ void bigram_loss(
    const int*   __restrict__ seq,
    const int*   __restrict__ pred,
    const float* __restrict__ emb,
    const float* __restrict__ W,
    const float* __restrict__ bias,
    const float* __restrict__ rowsum,
    float*       __restrict__ loss,
    int N)
{
    const int tid = threadIdx.x;
    float local = 0.f;
    for (int n = blockIdx.x * blockDim.x + tid; n < N; n += gridDim.x * blockDim.x) {
        const int r = seq[n], t = pred[n];
        const float4* e4 = reinterpret_cast<const float4*>(emb + (size_t)r * 32);
        const float4* w4 = reinterpret_cast<const float4*>(W + (size_t)t * 32);
        float d = bias[t];
#pragma unroll
        for (int i = 0; i < 8; ++i) {
            const float4 e = e4[i], w = w4[i];
            d += e.x * w.x + e.y * w.y + e.z * w.z + e.w * w.w;
        }
        local += __logf(rowsum[n]) - d;
    }
#pragma unroll
    for (int off = 32; off >= 1; off >>= 1) local += __shfl_xor(local, off, 64);
    __shared__ float r4[4];
    if ((tid & 63) == 0) r4[tid >> 6] = local;
    __syncthreads();
    if (tid == 0) {
        const float s = r4[0] + r4[1] + r4[2] + r4[3];
        atomicAdd(loss, s / (float)N);
    }
}

extern "C" void kernel_launch(void* const* d_in, const int* in_sizes, int n_in,
                              void* d_out, int out_size, void* d_ws, size_t ws_size,
                              hipStream_t stream)
{
    const int*   seq  = (const int*)d_in[0];
    const int*   pred = (const int*)d_in[1];
    const float* emb  = (const float*)d_in[2];
    const float* W    = (const float*)d_in[3];
    const float* bias = (const float*)d_in[4];

    const int N = in_sizes[0];      // 4096
    const int V = in_sizes[4];      // 100277

    float* logits = (float*)d_out;
    float* loss   = logits + (size_t)N * V;

    char*  ws     = (char*)d_ws;
    float* rowsum = (float*)(ws + RS_OFF);
    uint4* a_hi   = (uint4*)(ws + A_HI_OFF);
    uint4* a_lo   = (uint4*)(ws + A_LO_OFF);

    hipMemsetAsync((void*)rowsum, 0, (size_t)N * sizeof(float), stream);
    hipMemsetAsync((void*)loss, 0, sizeof(float), stream);

    hipLaunchKernelGGL(prep_afrag, dim3(CHUNKS * 64 / 256), dim3(256), 0, stream,
                       seq, emb, a_hi, a_lo);

    const int nColBlocks = (V + V_PER_BLOCK - 1) / V_PER_BLOCK;   // 392
    hipLaunchKernelGGL(bigram_mfma, dim3(nColBlocks * ROW_SPLITS), dim3(256), 0, stream,
                       W, bias, a_hi, a_lo, logits, rowsum, V, nColBlocks);

    hipLaunchKernelGGL(bigram_loss, dim3(16), dim3(256), 0, stream,
                       seq, pred, emb, W, bias, rowsum, loss, N);
}

// Round 4
// 609.534 us; speedup vs baseline: 26.0686x; 1.4732x over previous
//
#include <hip/hip_runtime.h>
#include <cstddef>
#include <cstdint>

// Bigram CE via MFMA: logits = emb[seq] @ W^T + b (fp32 via bf16 hi/lo split),
// fused exp-rowsum (block-local, NO global atomics), LDS-transposed 1KB stores.
// N=4096 rows, V=100277, K=32 (one 16x16x32 MFMA per tile, x3 for hi/lo).

using f32x4  = __attribute__((ext_vector_type(4))) float;
using bf16x8 = __attribute__((ext_vector_type(8))) __bf16;

static __device__ __forceinline__ unsigned short f2bf_rne(float f) {
    unsigned u = __float_as_uint(f);
    unsigned r = u + 0x7FFFu + ((u >> 16) & 1u);
    return (unsigned short)(r >> 16);
}
static __device__ __forceinline__ float bf2f(unsigned short h) {
    return __uint_as_float(((unsigned)h) << 16);
}
static __device__ __forceinline__ uint4 pack8(const unsigned short* h) {
    uint4 u;
    u.x = (unsigned)h[0] | ((unsigned)h[1] << 16);
    u.y = (unsigned)h[2] | ((unsigned)h[3] << 16);
    u.z = (unsigned)h[4] | ((unsigned)h[5] << 16);
    u.w = (unsigned)h[6] | ((unsigned)h[7] << 16);
    return u;
}

constexpr int N_ROWS = 4096;
constexpr int CHUNKS = N_ROWS / 16;                    // 256 row-chunks of 16
constexpr int TILES  = 4;                              // 16-col tiles per wave
constexpr int WAVES_PB = 4;
constexpr int V_PER_BLOCK = WAVES_PB * TILES * 16;     // 256 cols per block
constexpr int ROW_SPLITS = 4;
constexpr int CHUNKS_PER_SPLIT = CHUNKS / ROW_SPLITS;  // 64
constexpr int NCOLB = (100277 + V_PER_BLOCK - 1) / V_PER_BLOCK;  // 392

// d_ws layout (bytes)
constexpr size_t RS_OFF   = 0;                          // rowsum: 4096 f32
constexpr size_t A_HI_OFF = 16384;
constexpr size_t A_BYTES  = (size_t)CHUNKS * 64 * 16;   // 256 KB
constexpr size_t A_LO_OFF = A_HI_OFF + A_BYTES;
constexpr size_t PART_OFF = A_LO_OFF + A_BYTES;         // NCOLB*4096 f32 = 6.4 MB

// Pack A = emb[seq] into MFMA fragment order, hi/lo bf16.
// Fragment (16x16x32 A): lane l -> row = l&15, k = (l>>4)*8 .. +7 (contiguous).
__global__ __launch_bounds__(256) void prep_afrag(
    const int*   __restrict__ seq,
    const float* __restrict__ emb,
    uint4*       __restrict__ a_hi,
    uint4*       __restrict__ a_lo)
{
    const int g   = blockIdx.x * 256 + threadIdx.x;    // 16384 = CHUNKS*64
    const int l   = g & 63;
    const int c   = g >> 6;
    const int row = c * 16 + (l & 15);
    const int k0  = (l >> 4) * 8;
    const int idx = seq[row];

    const float* ep = emb + (size_t)idx * 32 + k0;
    float f[8];
    *reinterpret_cast<float4*>(f)     = *reinterpret_cast<const float4*>(ep);
    *reinterpret_cast<float4*>(f + 4) = *reinterpret_cast<const float4*>(ep + 4);

    unsigned short hs[8], ls[8];
#pragma unroll
    for (int i = 0; i < 8; ++i) {
        hs[i] = f2bf_rne(f[i]);
        ls[i] = f2bf_rne(f[i] - bf2f(hs[i]));
    }
    a_hi[g] = pack8(hs);
    a_lo[g] = pack8(ls);
}

__global__ __launch_bounds__(256) void bigram_mfma(
    const float* __restrict__ W,
    const float* __restrict__ bias,
    const uint4* __restrict__ a_hi,
    const uint4* __restrict__ a_lo,
    float*       __restrict__ logits,
    float*       __restrict__ part,     // [NCOLB][4096]
    int V, int nColBlocks)
{
    __shared__ float tile[16][260];     // padded stride: write conflicts 2-way (free)
    __shared__ float lparts[WAVES_PB][16];

    const int tid   = threadIdx.x;
    const int lane  = tid & 63;
    const int wid   = tid >> 6;
    const int colb  = blockIdx.x % nColBlocks;
    const int rsp   = blockIdx.x / nColBlocks;
    const int lgrp  = lane >> 4;        // 0..3
    const int lcol  = lane & 15;
    const int k0    = lgrp * 8;

    const int cbase0 = colb * V_PER_BLOCK;            // block's first column
    const int cbase  = cbase0 + wid * (TILES * 16);   // wave's first column

    // B fragments (W columns) -> registers, hi/lo split. Lane l: col = lane&15,
    // k = (lane>>4)*8..+7 contiguous = W[col][k0..k0+7] (W is B^T row-major).
    bf16x8 bhi[TILES], blo[TILES];
    float  bval[TILES];
    bool   ok[TILES];
#pragma unroll
    for (int t = 0; t < TILES; ++t) {
        const int col = cbase + t * 16 + lcol;
        ok[t] = (col < V);
        const int cc = ok[t] ? col : V - 1;
        const float* wp = W + (size_t)cc * 32 + k0;
        float f[8];
        *reinterpret_cast<float4*>(f)     = *reinterpret_cast<const float4*>(wp);
        *reinterpret_cast<float4*>(f + 4) = *reinterpret_cast<const float4*>(wp + 4);
        unsigned short hs[8], ls[8];
#pragma unroll
        for (int i = 0; i < 8; ++i) {
            hs[i] = f2bf_rne(f[i]);
            ls[i] = f2bf_rne(f[i] - bf2f(hs[i]));
        }
        const uint4 H = pack8(hs), L = pack8(ls);
        bhi[t]  = __builtin_bit_cast(bf16x8, H);
        blo[t]  = __builtin_bit_cast(bf16x8, L);
        bval[t] = bias[cc];
    }

    const int c_begin = rsp * CHUNKS_PER_SPLIT;
    for (int c = c_begin; c < c_begin + CHUNKS_PER_SPLIT; ++c) {
        const uint4 AH = a_hi[c * 64 + lane];
        const uint4 AL = a_lo[c * 64 + lane];
        const bf16x8 ah = __builtin_bit_cast(bf16x8, AH);
        const bf16x8 al = __builtin_bit_cast(bf16x8, AL);

        f32x4 acc[TILES];
#pragma unroll
        for (int t = 0; t < TILES; ++t) {
            f32x4 a0 = {bval[t], bval[t], bval[t], bval[t]};  // bias as C-init
            a0 = __builtin_amdgcn_mfma_f32_16x16x32_bf16(ah, bhi[t], a0, 0, 0, 0);
            a0 = __builtin_amdgcn_mfma_f32_16x16x32_bf16(al, bhi[t], a0, 0, 0, 0);
            a0 = __builtin_amdgcn_mfma_f32_16x16x32_bf16(ah, blo[t], a0, 0, 0, 0);
            acc[t] = a0;
        }

        // C/D layout (m89-verified): col = lane&15, row_local = (lane>>4)*4 + j.
        // Stage into LDS + per-row exp-partials (16-lane reduce, leader -> LDS).
#pragma unroll
        for (int j = 0; j < 4; ++j) {
            const int rl = lgrp * 4 + j;
            float s = 0.f;
#pragma unroll
            for (int t = 0; t < TILES; ++t) {
                const float x = acc[t][j];
                tile[rl][wid * 64 + t * 16 + lcol] = x;
                if (ok[t]) s += __expf(x);
            }
            s += __shfl_xor(s, 1, 64);
            s += __shfl_xor(s, 2, 64);
            s += __shfl_xor(s, 4, 64);
            s += __shfl_xor(s, 8, 64);
            if (lcol == 0) lparts[wid][rl] = s;
        }
        __syncthreads();

        // Coalesced stores: each wave stores 4 rows, 1KB (64 lanes x dwordx4) each.
        const int rowg = c * 16;
#pragma unroll
        for (int r = 0; r < 4; ++r) {
            const int rl = wid * 4 + r;
            const float4 x4 = *reinterpret_cast<const float4*>(&tile[rl][lane * 4]);
            const int col = cbase0 + lane * 4;
            float* dst = logits + (size_t)(rowg + rl) * V + col;
            if (col + 3 < V) {
                *reinterpret_cast<float4*>(dst) = x4;
            } else {
                if (col     < V) dst[0] = x4.x;
                if (col + 1 < V) dst[1] = x4.y;
                if (col + 2 < V) dst[2] = x4.z;
            }
        }
        // One partial per (colBlock,row), written once: no atomics anywhere.
        if (wid == 0 && lane < 16) {
            part[(size_t)colb * N_ROWS + rowg + lane] =
                lparts[0][lane] + lparts[1][lane] + lparts[2][lane] + lparts[3][lane];
        }
        __syncthreads();   // protect tile/lparts before next chunk overwrites
    }
}

// rowsum[n] = sum over column blocks of part[cb][n]  (coalesced across threads)
__global__ __launch_bounds__(256) void reduce_rowsum(
    const float* __restrict__ part,
    float*       __restrict__ rowsum,
    int nColBlocks, int N)
{
    const int n = blockIdx.x * 256 + threadIdx.x;
    if (n >= N) return;
    float s = 0.f;
#pragma unroll 4
    for (int p = 0; p < nColBlocks; ++p) s += part[(size_t)p * N + n];
    rowsum[n] = s;
}

// loss = mean( log(rowsum[n]) - (dot(emb[seq[n]], W[pred[n]]) + b[pred[n]]) )
__global__ void bigram_loss(
    const int*   __restrict__ seq,
    const int*   __restrict__ pred,
    const float* __restrict__ emb,
    const float* __restrict__ W,
    const float* __restrict__ bias,
    const float* __restrict__ rowsum,
    float*       __restrict__ loss,
    int N)
{
    const int tid = threadIdx.x;
    float local = 0.f;
    for (int n = blockIdx.x * blockDim.x + tid; n < N; n += gridDim.x * blockDim.x) {
        const int r = seq[n], t = pred[n];
        const float4* e4 = reinterpret_cast<const float4*>(emb + (size_t)r * 32);
        const float4* w4 = reinterpret_cast<const float4*>(W + (size_t)t * 32);
        float d = bias[t];
#pragma unroll
        for (int i = 0; i < 8; ++i) {
            const float4 e = e4[i], w = w4[i];
            d += e.x * w.x + e.y * w.y + e.z * w.z + e.w * w.w;
        }
        local += __logf(rowsum[n]) - d;
    }
#pragma unroll
    for (int off = 32; off >= 1; off >>= 1) local += __shfl_xor(local, off, 64);
    __shared__ float r4[4];
    if ((tid & 63) == 0) r4[tid >> 6] = local;
    __syncthreads();
    if (tid == 0) {
        const float s = r4[0] + r4[1] + r4[2] + r4[3];
        atomicAdd(loss, s / (float)N);
    }
}

extern "C" void kernel_launch(void* const* d_in, const int* in_sizes, int n_in,
                              void* d_out, int out_size, void* d_ws, size_t ws_size,
                              hipStream_t stream)
{
    const int*   seq  = (const int*)d_in[0];
    const int*   pred = (const int*)d_in[1];
    const float* emb  = (const float*)d_in[2];
    const float* W    = (const float*)d_in[3];
    const float* bias = (const float*)d_in[4];

    const int N = in_sizes[0];      // 4096
    const int V = in_sizes[4];      // 100277

    float* logits = (float*)d_out;
    float* loss   = logits + (size_t)N * V;

    char*  ws     = (char*)d_ws;
    float* rowsum = (float*)(ws + RS_OFF);
    uint4* a_hi   = (uint4*)(ws + A_HI_OFF);
    uint4* a_lo   = (uint4*)(ws + A_LO_OFF);
    float* part   = (float*)(ws + PART_OFF);

    hipMemsetAsync((void*)loss, 0, sizeof(float), stream);

    hipLaunchKernelGGL(prep_afrag, dim3(CHUNKS * 64 / 256), dim3(256), 0, stream,
                       seq, emb, a_hi, a_lo);

    hipLaunchKernelGGL(bigram_mfma, dim3(NCOLB * ROW_SPLITS), dim3(256), 0, stream,
                       W, bias, a_hi, a_lo, logits, part, V, NCOLB);

    hipLaunchKernelGGL(reduce_rowsum, dim3((N + 255) / 256), dim3(256), 0, stream,
                       part, rowsum, NCOLB, N);

    hipLaunchKernelGGL(bigram_loss, dim3(16), dim3(256), 0, stream,
                       seq, pred, emb, W, bias, rowsum, loss, N);
}